// Round 6
// baseline (231.384 us; speedup 1.0000x reference)
//
#include <hip/hip_runtime.h>

// Problem constants (fixed by setup_inputs)
#define DIM 512
#define NQ 64
#define BATCH 2048

typedef __bf16  bf16x8  __attribute__((ext_vector_type(8)));
typedef float   floatx4 __attribute__((ext_vector_type(4)));

static __device__ inline unsigned short f2bf(float f) {
    unsigned int u = __float_as_uint(f);
    return (unsigned short)((u + 0x7fffu + ((u >> 16) & 1u)) >> 16);  // RNE
}
static __device__ inline float bf2f(unsigned short h) {
    return __uint_as_float((unsigned int)h << 16);
}
static __device__ inline unsigned int pack2(float a, float b) {
    return (unsigned)f2bf(a) | ((unsigned)f2bf(b) << 16);
}

// Fused pack+expand v5 (proven: cut non-GEMM residual 86 -> 61 us). Grid (512,5):
//   y = 0..3 : expand q_coefs -> W[k][e][d] + npart partials (float4 loads,
//              in-register 4x4 k<->d transpose via shfl_xor)
//   y = 4    : pack points fp32 -> bf16 Pb
__global__ __launch_bounds__(512, 3)
void hsq_expand_kernel(const float* __restrict__ qc,
                       const float* __restrict__ pts,
                       unsigned short* __restrict__ W,
                       unsigned short* __restrict__ Pb,
                       float* __restrict__ npart) {
    const int e = blockIdx.x;             // 0..511

    if (blockIdx.y == 4) {
        const int i4 = e * 512 + threadIdx.x;
        const float4 v = *(const float4*)(pts + (size_t)i4 * 4);
        uint2 wv;
        wv.x = pack2(v.x, v.y); wv.y = pack2(v.z, v.w);
        *(uint2*)(Pb + (size_t)i4 * 4) = wv;
        return;
    }

    const int dblk = blockIdx.y;          // 0..3
    const int pb   = dblk * 512 + e;      // 0..2047
    const int tid  = threadIdx.x;
    const int w    = tid >> 6;            // 0..7
    const int lane = tid & 63;
    const int g    = lane >> 4;           // row-slot 0..3 (pre-transpose)
    const int u    = lane & 15;           // k-quad 0..15
    const int d0   = dblk * 128;

    __shared__ unsigned short tv[64 * 136];   // [k][136] (16B-aligned rows)
    __shared__ float part2[8][64];

    float4 nacc4 = {0.f, 0.f, 0.f, 0.f};

#pragma unroll
    for (int p = 0; p < 4; ++p) {
        const int rloc = p * 32 + w * 4;  // wave's 4-row base this pass
        const int d = d0 + rloc + g;      // this lane's row (pre-transpose)
        const int i = d < e ? d : e;
        const int j = d < e ? e : d;
        const int idx = i * DIM - ((i * (i - 1)) >> 1) + (j - i);
        float4 f = *(const float4*)(qc + (size_t)idx * NQ + u * 4);

        if (d >= e) {
            nacc4.x += f.x * f.x; nacc4.y += f.y * f.y;
            nacc4.z += f.z * f.z; nacc4.w += f.w * f.w;
        }
        const float s = (d == e) ? 2.0f : 1.41421356237309515f;
        float4 v = {f.x * s, f.y * s, f.z * s, f.w * s};

        // 4x4 transpose across quartet lanes {u, u+16, u+32, u+48}
        {
            float s0 = (g & 2) ? v.x : v.z;
            float s1 = (g & 2) ? v.y : v.w;
            const float r0 = __shfl_xor(s0, 32);
            const float r1 = __shfl_xor(s1, 32);
            if (g & 2) { v.x = r0; v.y = r1; } else { v.z = r0; v.w = r1; }
        }
        {
            float s0 = (g & 1) ? v.x : v.y;
            float s1 = (g & 1) ? v.z : v.w;
            const float r0 = __shfl_xor(s0, 16);
            const float r1 = __shfl_xor(s1, 16);
            if (g & 1) { v.x = r0; v.z = r1; } else { v.y = r0; v.w = r1; }
        }
        const int k = u * 4 + g;
        uint2 wv;
        wv.x = pack2(v.x, v.y);
        wv.y = pack2(v.z, v.w);
        *(uint2*)&tv[k * 136 + rloc] = wv;
    }

    nacc4.x += __shfl_xor(nacc4.x, 16); nacc4.y += __shfl_xor(nacc4.y, 16);
    nacc4.z += __shfl_xor(nacc4.z, 16); nacc4.w += __shfl_xor(nacc4.w, 16);
    nacc4.x += __shfl_xor(nacc4.x, 32); nacc4.y += __shfl_xor(nacc4.y, 32);
    nacc4.z += __shfl_xor(nacc4.z, 32); nacc4.w += __shfl_xor(nacc4.w, 32);
    if (g == 0) *(float4*)&part2[w][u * 4] = nacc4;
    __syncthreads();

#pragma unroll
    for (int r = 0; r < 2; ++r) {
        const int kk = r * 32 + (tid >> 4);
        const int uu = tid & 15;
        const uint4 ww = *(const uint4*)&tv[kk * 136 + uu * 8];
        *(uint4*)(W + ((size_t)(kk * DIM + e)) * DIM + dblk * 128 + uu * 8) = ww;
    }
    if (tid < 64) {
        npart[(size_t)tid * 2048 + pb] =
            part2[0][tid] + part2[1][tid] + part2[2][tid] + part2[3][tid] +
            part2[4][tid] + part2[5][tid] + part2[6][tid] + part2[7][tid];
    }
}

// ---------------------------------------------------------------------------
// GEMM v6: 16 WAVES (1024 threads), per-wave 64x64, BM=BN=256, BK=64.
// Rationale: all 8-wave variants had VGPR_Count=128 @ 2 waves/SIMD = RF HALF
// EMPTY and pinned at 26-27% MfmaUtil. 16 waves x ~125 VGPR fills the RF:
// 4 waves/SIMD of latency-hiding material inside each barrier phase.
// acc = 4x4 floatx4 (64 VGPR) + bfr[4][2] (32) + afr[4] (16) ~= 125.
// Same 128 KiB LDS (2buf x {A 32KB, B 32KB}), same XOR swizzle (both sides),
// same grid/XCD mapping as the proven R1/R3 kernel (FETCH ~25 MB).
// K-loop: 4 phases per 2 K-tiles; B frags of a tile load whole-tile (frees
// buf.B for restage); counted vmcnt ledger (per-thread outstanding):
//   entering ph0(iter i): {B(2i+1)->buf1} = 2 in flight
//   ph0: +A(2i+1)->buf1 (4)   | compute buf0 kh0
//   ph1: +B(2i+2)->buf0 (6); vmcnt(2) => buf1 complete  | buf0 kh1
//   ph2: +A(2i+2)->buf0 (4)   | buf1 kh0
//   ph3: +B(2i+3)->buf1 (6); vmcnt(2) => buf0 complete  | buf1 kh1
// i=3: no stages past tile7; ph1 uses vmcnt(0) (drain), ph3 no wait.
// Write-after-read: every restage targets a region last read before the
// preceding exit barrier (B freed by whole-tile LOADB at ph0/ph2).
// ---------------------------------------------------------------------------
__global__ __launch_bounds__(1024, 4)
void hsq_gemm_kernel(const unsigned short* __restrict__ Pb,
                     const unsigned short* __restrict__ W,
                     const float* __restrict__ l_coefs,
                     float2* __restrict__ part) {
    extern __shared__ unsigned short smem[];

    // bijective XCD swizzle (1024 % 8 == 0): consecutive wg on one XCD share k
    const int bid = blockIdx.x;
    const int wg  = (bid & 7) * 128 + (bid >> 3);
    const int k   = wg >> 4;              // 0..63
    const int rem = wg & 15;
    const int et  = rem >> 3;             // 0..1  (e-tile of 256)
    const int mt  = rem & 7;              // 0..7  (batch tile of 256)
    const int m0  = mt * 256;

    const int tid  = threadIdx.x;
    const int lane = tid & 63;
    const int w    = tid >> 6;            // 0..15
    const int wm   = w >> 2;              // 0..3 (M group of 64)
    const int wn   = w & 3;               // 0..3 (N group of 64)
    const int c    = lane & 15;
    const int quad = lane >> 4;

    const unsigned short* Wk = W + ((size_t)k * DIM + (size_t)et * 256) * DIM;

    // staging source (linear LDS dest; source carries the swizzle involution)
    const int scolb = ((tid & 7) * 16) ^ (((tid >> 3) & 7) << 4);   // bytes
    const unsigned short* pAs = Pb + (size_t)(m0 + (tid >> 3)) * DIM + (scolb >> 1);
    const unsigned short* pBs = Wk + (size_t)(tid >> 3) * DIM + (scolb >> 1);

    // frag read offsets (elements); row&7 == c&7 for every frag row
    const int koff0 = ((0 * 64 + quad * 16) ^ ((c & 7) << 4)) >> 1;
    const int koff1 = ((1 * 64 + quad * 16) ^ ((c & 7) << 4)) >> 1;
    const int awoff = wm * 4096 + c * 64;     // wave M-block of 64 rows
    const int bwoff = wn * 4096 + c * 64;     // wave N-block of 64 rows

#define AELEM(BUF) ((BUF) * 32768)
#define BELEM(BUF) ((BUF) * 32768 + 16384)

// one 1024-thread gload_lds instr = 128 rows x 64 cols = 16 KB; two = full tile
#define STAGE2(DSTELEM, GSRC) do {                                             \
    __builtin_amdgcn_global_load_lds(                                          \
        (const __attribute__((address_space(1))) unsigned int*)(GSRC),         \
        (__attribute__((address_space(3))) unsigned int*)                      \
            (smem + (DSTELEM) + tid * 8), 16, 0, 0);                           \
    __builtin_amdgcn_global_load_lds(                                          \
        (const __attribute__((address_space(1))) unsigned int*)                \
            ((GSRC) + 128 * DIM),                                              \
        (__attribute__((address_space(3))) unsigned int*)                      \
            (smem + (DSTELEM) + 8192 + tid * 8), 16, 0, 0);                    \
} while (0)

#define LOADB(BUF) do {                                                        \
    _Pragma("unroll")                                                          \
    for (int ni_ = 0; ni_ < 4; ++ni_) {                                        \
        bfr[ni_][0] = *(const bf16x8*)(smem + BELEM(BUF) + bwoff + ni_ * 1024 + koff0); \
        bfr[ni_][1] = *(const bf16x8*)(smem + BELEM(BUF) + bwoff + ni_ * 1024 + koff1); \
    }                                                                          \
} while (0)

#define PHASE(BUF, KH, PRE_B, STAGE_AND_WAIT) do {                             \
    bf16x8 afr[4];                                                             \
    _Pragma("unroll")                                                          \
    for (int mi_ = 0; mi_ < 4; ++mi_)                                          \
        afr[mi_] = *(const bf16x8*)(smem + AELEM(BUF) + awoff + mi_ * 1024 +   \
                                    ((KH) ? koff1 : koff0));                   \
    PRE_B;                                                                     \
    STAGE_AND_WAIT;                                                            \
    asm volatile("" ::: "memory");                                             \
    __builtin_amdgcn_s_barrier();                                              \
    asm volatile("" ::: "memory");                                             \
    __builtin_amdgcn_s_setprio(1);                                             \
    _Pragma("unroll")                                                          \
    for (int mi_ = 0; mi_ < 4; ++mi_)                                          \
        _Pragma("unroll")                                                      \
        for (int ni_ = 0; ni_ < 4; ++ni_)                                      \
            acc[mi_][ni_] = __builtin_amdgcn_mfma_f32_16x16x32_bf16(           \
                afr[mi_], bfr[ni_][KH], acc[mi_][ni_], 0, 0, 0);               \
    __builtin_amdgcn_s_setprio(0);                                             \
    asm volatile("" ::: "memory");                                             \
    __builtin_amdgcn_s_barrier();                                              \
    asm volatile("" ::: "memory");                                             \
} while (0)

#define VM2  asm volatile("s_waitcnt vmcnt(2)" ::: "memory")
#define VM0  asm volatile("s_waitcnt vmcnt(0)" ::: "memory")

    floatx4 acc[4][4];
#pragma unroll
    for (int mi = 0; mi < 4; ++mi)
#pragma unroll
        for (int ni = 0; ni < 4; ++ni)
            acc[mi][ni] = (floatx4){0.f, 0.f, 0.f, 0.f};

    bf16x8 bfr[4][2];

    // prologue: buf0 = tile0 (A+B), buf1.B = tile1's B; wait tile0, leave B(1)
    STAGE2(AELEM(0), pAs);
    STAGE2(BELEM(0), pBs);
    STAGE2(BELEM(1), pBs + 64);
    VM2;
    __builtin_amdgcn_s_barrier();
    asm volatile("" ::: "memory");

#pragma unroll 1
    for (int it = 0; it < 4; ++it) {
        const unsigned short* pA1 = pAs + (size_t)(2 * it + 1) * 64;
        const unsigned short* pA2 = pAs + (size_t)(2 * it + 2) * 64;
        const unsigned short* pB2 = pBs + (size_t)(2 * it + 2) * 64;
        const unsigned short* pB3 = pBs + (size_t)(2 * it + 3) * 64;

        // ph0: tile 2it kh0 (buf0); stage A(2it+1)->buf1.A
        PHASE(0, 0, LOADB(0), { STAGE2(AELEM(1), pA1); });
        // ph1: tile 2it kh1 (buf0); stage B(2it+2)->buf0.B; buf1 complete
        PHASE(0, 1, ((void)0), {
            if (it < 3) { STAGE2(BELEM(0), pB2); VM2; } else { VM0; }
        });
        // ph2: tile 2it+1 kh0 (buf1); stage A(2it+2)->buf0.A
        PHASE(1, 0, LOADB(1), { if (it < 3) STAGE2(AELEM(0), pA2); });
        // ph3: tile 2it+1 kh1 (buf1); stage B(2it+3)->buf1.B; buf0 complete
        PHASE(1, 1, ((void)0), {
            if (it < 3) { STAGE2(BELEM(1), pB3); VM2; }
        });
    }
#undef PHASE
#undef LOADB
#undef STAGE2
#undef AELEM
#undef BELEM
#undef VM2
#undef VM0

    __syncthreads();

    // ---- Epilogue: pv = sum_e p*(0.5g+l), pg = sum_e (g+l)^2 over this et ----
    float lcv[4];
#pragma unroll
    for (int ni = 0; ni < 4; ++ni)
        lcv[ni] = l_coefs[(et * 256 + wn * 64 + ni * 16 + c) * NQ + k];

    const unsigned short* Pe = Pb + (size_t)(m0 + wm * 64) * DIM + et * 256 + wn * 64 + c;
    float* red = (float*)smem;   // 4 wn-groups x 256 rows x {pv,pg} = 8 KB

#pragma unroll
    for (int mi = 0; mi < 4; ++mi)
#pragma unroll
        for (int r = 0; r < 4; ++r) {
            const unsigned short* Prow = Pe + (size_t)(mi * 16 + quad * 4 + r) * DIM;
            float pv = 0.f, pg = 0.f;
#pragma unroll
            for (int ni = 0; ni < 4; ++ni) {
                const float g = acc[mi][ni][r];
                const float l = lcv[ni];
                pv += bf2f(Prow[ni * 16]) * (0.5f * g + l);
                const float gq = g + l;
                pg += gq * gq;
            }
#pragma unroll
            for (int off = 1; off < 16; off <<= 1) {
                pv += __shfl_xor(pv, off);
                pg += __shfl_xor(pg, off);
            }
            if (c == 0) {
                const int row = wm * 64 + mi * 16 + quad * 4 + r;   // 0..255
                red[(wn * 256 + row) * 2 + 0] = pv;
                red[(wn * 256 + row) * 2 + 1] = pg;
            }
        }
    __syncthreads();

    if (tid < 256) {
        float pv = 0.f, pg = 0.f;
#pragma unroll
        for (int wnf = 0; wnf < 4; ++wnf) {
            pv += red[(wnf * 256 + tid) * 2 + 0];
            pg += red[(wnf * 256 + tid) * 2 + 1];
        }
        part[((size_t)(et * NQ + k)) * BATCH + m0 + tid] = make_float2(pv, pg);
    }
}

// Final: block per k. Reduces npart[k][*] -> norm2 in-block, then combines the
// 2 e-range partials into scores (coalesced reads).
__global__ void hsq_final_kernel(const float2* __restrict__ part,
                                 const float* __restrict__ npart,
                                 const float* __restrict__ free_coefs,
                                 float* __restrict__ out) {
    const int k = blockIdx.x;
    const int t = threadIdx.x;
    __shared__ float ws[4];

    const float4* src = (const float4*)(npart + (size_t)k * 2048);
    const float4 a = src[t * 2], b = src[t * 2 + 1];
    float s = a.x + a.y + a.z + a.w + b.x + b.y + b.z + b.w;
#pragma unroll
    for (int off = 1; off < 64; off <<= 1) s += __shfl_xor(s, off);
    if ((t & 63) == 0) ws[t >> 6] = s;
    __syncthreads();
    const float nrm = sqrtf(ws[0] + ws[1] + ws[2] + ws[3]);
    const float fc  = free_coefs[k];

#pragma unroll
    for (int i = 0; i < 8; ++i) {
        const int bidx = i * 256 + t;
        float pv = 0.f, pg = 0.f;
#pragma unroll
        for (int eb = 0; eb < 2; ++eb) {
            const float2 p = part[((size_t)(eb * NQ + k)) * BATCH + bidx];
            pv += p.x; pg += p.y;
        }
        const float vals = fabsf(pv + fc);
        out[(size_t)bidx * NQ + k] = (sqrtf(0.25f * pg + vals * nrm) - 0.5f * sqrtf(pg)) / nrm;
    }
}

extern "C" void kernel_launch(void* const* d_in, const int* in_sizes, int n_in,
                              void* d_out, int out_size, void* d_ws, size_t ws_size,
                              hipStream_t stream) {
    const float* points     = (const float*)d_in[0];  // (2048, 512)
    const float* q_coefs    = (const float*)d_in[1];  // (131328, 64)
    const float* l_coefs    = (const float*)d_in[2];  // (512, 64)
    const float* free_coefs = (const float*)d_in[3];  // (1, 64)
    float* out = (float*)d_out;                       // (2048, 64)

    char* ws = (char*)d_ws;
    unsigned short* W  = (unsigned short*)ws;                              // 32 MiB
    unsigned short* Pb = (unsigned short*)(ws + 33554432);                 // 2 MiB
    float2*         part  = (float2*)(ws + 35651584);                      // 2 MiB
    float*          npart = (float*)(ws + 37748736);                       // 512 KiB

    // 128 KiB dynamic LDS needs the opt-in (one-time; not a stream op, safe
    // under graph capture).
    static bool attr_done = false;
    if (!attr_done) {
        (void)hipFuncSetAttribute((const void*)hsq_gemm_kernel,
                                  hipFuncAttributeMaxDynamicSharedMemorySize,
                                  131072);
        attr_done = true;
    }

    hsq_expand_kernel<<<dim3(512, 5), 512, 0, stream>>>(q_coefs, points, W, Pb, npart);
    hsq_gemm_kernel<<<dim3(1024), dim3(1024), 131072, stream>>>(Pb, W, l_coefs, part);
    hsq_final_kernel<<<dim3(NQ), 256, 0, stream>>>(part, npart, free_coefs, out);
}